// Round 1
// baseline (580.523 us; speedup 1.0000x reference)
//
#include <hip/hip_runtime.h>

#define BSZn 16
#define SEQn 2048
#define DIN 256
#define DST 1024
#define DOUTn 256
#define KXn 10
#define TCH 64
#define NCH 32

typedef __attribute__((ext_vector_type(4))) float f32x4;
typedef __attribute__((ext_vector_type(8))) short bf16x8;

__device__ __forceinline__ unsigned short f2bf(float f){
  unsigned u = __float_as_uint(f);
  u += 0x7FFF + ((u>>16)&1);
  return (unsigned short)(u>>16);
}
__device__ __forceinline__ float bf2f(unsigned short s){
  return __uint_as_float(((unsigned)s)<<16);
}

// swizzled LDS index for [*][256]-bf16 tiles (row stride 512B) and [*][128] (256B)
#define XIDX(r,c) ((((r)<<8) + (c)) ^ (((r)&7)<<3))
#define UIDX(r,c) ((((r)<<7) + (c)) ^ (((r)&7)<<3))

// ---------------- K0: weight prep (transpose + fp32->bf16) ----------------
__global__ void k_prep(const float* __restrict__ B, const float* __restrict__ C,
                       const float* __restrict__ M, unsigned short* __restrict__ Bt,
                       unsigned short* __restrict__ Ct, unsigned short* __restrict__ Mt){
  int stride = gridDim.x*blockDim.x;
  int i0 = blockIdx.x*blockDim.x + threadIdx.x;
  for(int idx=i0; idx<DIN*DST; idx+=stride){
    int s = idx >> 8, d = idx & 255;
    Bt[idx] = f2bf(B[d*DST + s]);          // Bt[s][d]
    int o = idx >> 10, ss = idx & 1023;
    Ct[idx] = f2bf(C[ss*DOUTn + o]);       // Ct[o][s]
  }
  for(int idx=i0; idx<DOUTn*DIN*KXn; idx+=stride){
    int o = idx/2560, k = idx%2560, ii = k>>8, j = k&255;
    Mt[idx] = f2bf(M[(o*DIN+j)*KXn + ii]); // Mt[o][i*256+j]
  }
}

// ---------------- K_AR: out = unfold(x) @ Mt ----------------
__global__ __launch_bounds__(256) void k_ar(const float* __restrict__ x,
                                            const unsigned short* __restrict__ Mt,
                                            float* __restrict__ out){
  __shared__ __align__(16) unsigned short xt[73*256];
  int wg = blockIdx.x;
  int b = wg >> 5, c = wg & 31;
  int t0 = c*TCH;
  const float* xb = x + (size_t)b*SEQn*DIN;
  int tid = threadIdx.x;
  for(int e = tid; e < 73*64; e += 256){
    int r = e >> 6, c4 = (e & 63) << 2;
    int t = t0 - 9 + r;
    float4 v = {0.f,0.f,0.f,0.f};
    if(t >= 0) v = *(const float4*)(xb + t*DIN + c4);
    ushort4 w; w.x=f2bf(v.x); w.y=f2bf(v.y); w.z=f2bf(v.z); w.w=f2bf(v.w);
    *(ushort4*)&xt[XIDX(r, c4)] = w;
  }
  __syncthreads();
  int wv = tid >> 6, ln = tid & 63;
  int lm = ln & 15, lk = (ln >> 4) << 3;
  f32x4 zf = {0.f,0.f,0.f,0.f};
  f32x4 acc[4][4];
  #pragma unroll
  for(int tt=0;tt<4;tt++)
    #pragma unroll
    for(int nt=0;nt<4;nt++) acc[tt][nt] = zf;
  for(int i=0;i<KXn;i++){
    #pragma unroll
    for(int kb8=0;kb8<8;kb8++){
      int col = (kb8<<5) + lk;
      bf16x8 af[4];
      #pragma unroll
      for(int tt=0;tt<4;tt++){
        int r = (tt<<4) + lm + 9 - i;
        af[tt] = *(const bf16x8*)&xt[XIDX(r, col)];
      }
      #pragma unroll
      for(int nt=0;nt<4;nt++){
        int o = (wv<<6) + (nt<<4) + lm;
        bf16x8 bfr = *(const bf16x8*)&Mt[o*2560 + (i<<8) + col];
        #pragma unroll
        for(int tt=0;tt<4;tt++)
          acc[tt][nt] = __builtin_amdgcn_mfma_f32_16x16x32_bf16(af[tt], bfr, acc[tt][nt], 0,0,0);
      }
    }
  }
  int rr = (ln>>4)<<2;
  #pragma unroll
  for(int tt=0;tt<4;tt++)
    #pragma unroll
    for(int nt=0;nt<4;nt++)
      #pragma unroll
      for(int r4=0;r4<4;r4++){
        int m = (tt<<4) + rr + r4;
        int o = (wv<<6) + (nt<<4) + lm;
        out[((size_t)b*SEQn + t0 + m)*DOUTn + o] = acc[tt][nt][r4];
      }
}

// ---------------- K1: chunk partials P[b][c][s] ----------------
__global__ __launch_bounds__(256) void k_part(const float* __restrict__ x,
    const unsigned short* __restrict__ Bt, const float* __restrict__ A,
    float* __restrict__ P){
  __shared__ __align__(16) unsigned short xt[64*256];
  __shared__ __align__(16) unsigned short ub[64*128];
  int wg = blockIdx.x;
  int b = wg >> 5, c = wg & 31;
  int ts = c*TCH - 54;                      // rows ts .. ts+63  (= c*64+9 last)
  const float* xb = x + (size_t)b*SEQn*DIN;
  int tid = threadIdx.x;
  for(int e = tid; e < 64*64; e += 256){
    int r = e >> 6, c4 = (e & 63) << 2;
    int t = ts + r;
    float4 v = {0.f,0.f,0.f,0.f};
    if(t >= 0) v = *(const float4*)(xb + t*DIN + c4);
    ushort4 w; w.x=f2bf(v.x); w.y=f2bf(v.y); w.z=f2bf(v.z); w.w=f2bf(v.w);
    *(ushort4*)&xt[XIDX(r,c4)] = w;
  }
  int wv = tid>>6, ln = tid&63, lm = ln&15, lk = (ln>>4)<<3;
  int rr = (ln>>4)<<2;
  for(int e8=0;e8<8;e8++){
    __syncthreads();
    bf16x8 af[8];
    #pragma unroll
    for(int kb=0;kb<8;kb++)
      af[kb] = *(const bf16x8*)&xt[XIDX((wv<<4)+lm, (kb<<5)+lk)];
    #pragma unroll
    for(int st=0;st<8;st++){
      f32x4 a = {0.f,0.f,0.f,0.f};
      int sg = (e8<<7) + (st<<4) + lm;
      #pragma unroll
      for(int kb=0;kb<8;kb++){
        bf16x8 bfr = *(const bf16x8*)&Bt[(sg<<8) + (kb<<5) + lk];
        a = __builtin_amdgcn_mfma_f32_16x16x32_bf16(af[kb], bfr, a, 0,0,0);
      }
      #pragma unroll
      for(int r4=0;r4<4;r4++)
        ub[UIDX((wv<<4)+rr+r4, (st<<4)+lm)] = f2bf(a[r4]);
    }
    __syncthreads();
    if(tid < 128){
      int s = (e8<<7) + tid;
      float Av = A[s];
      float p = 0.f;
      #pragma unroll
      for(int t=0;t<64;t++)
        p = Av*p + bf2f(ub[UIDX(t, tid)]);
      P[(((b<<5)+c)<<10) + s] = p;
    }
  }
}

// ---------------- K2: boundary states ----------------
__global__ void k_bound(const float* __restrict__ A, const float* __restrict__ h0,
                        const float* __restrict__ P, float* __restrict__ bound){
  int i = blockIdx.x*blockDim.x + threadIdx.x;
  if(i >= BSZn*DST) return;
  int b = i >> 10, s = i & 1023;
  float Av = A[s];
  float a2=Av*Av, a4=a2*a2, a8=a4*a4;
  float a10=a8*a2, a16=a8*a8, a32=a16*a16, a64=a32*a32;
  const float* Pb = P + ((size_t)(b<<5)<<10);
  float* Bb = bound + ((size_t)(b<<5)<<10);
  float h = a10*h0[s] + Pb[s];
  Bb[s] = h;
  for(int c=1;c<NCH;c++){
    h = a64*h + Pb[(c<<10)+s];
    Bb[(c<<10)+s] = h;
  }
}

// ---------------- K3: scan chunk + h@C, accumulate onto out ----------------
__global__ __launch_bounds__(256) void k_scanc(const float* __restrict__ x,
    const unsigned short* __restrict__ Bt, const unsigned short* __restrict__ Ct,
    const float* __restrict__ A, const float* __restrict__ bound,
    float* __restrict__ out){
  __shared__ __align__(16) unsigned short xt[64*256];
  __shared__ __align__(16) unsigned short ub[64*128];
  int wg = blockIdx.x;
  int b = wg>>5, c = wg&31;
  int t0 = c*TCH;
  const float* xb = x + (size_t)b*SEQn*DIN;
  int tid = threadIdx.x;
  for(int e = tid; e < 64*64; e += 256){
    int r = e>>6, c4 = (e&63)<<2;
    int t = t0 + 10 + r;
    float4 v = {0.f,0.f,0.f,0.f};
    if(t < SEQn) v = *(const float4*)(xb + t*DIN + c4);
    ushort4 w; w.x=f2bf(v.x); w.y=f2bf(v.y); w.z=f2bf(v.z); w.w=f2bf(v.w);
    *(ushort4*)&xt[XIDX(r,c4)] = w;
  }
  int wv=tid>>6, ln=tid&63, lm=ln&15, lk=(ln>>4)<<3;
  int rr=(ln>>4)<<2;
  f32x4 zf = {0.f,0.f,0.f,0.f};
  f32x4 accC[16];
  #pragma unroll
  for(int nt=0;nt<16;nt++) accC[nt] = zf;
  for(int e8=0;e8<8;e8++){
    __syncthreads();
    // uB GEMM for this s-eighth
    bf16x8 af[8];
    #pragma unroll
    for(int kb=0;kb<8;kb++)
      af[kb] = *(const bf16x8*)&xt[XIDX((wv<<4)+lm, (kb<<5)+lk)];
    #pragma unroll
    for(int st=0;st<8;st++){
      f32x4 a = {0.f,0.f,0.f,0.f};
      int sg = (e8<<7) + (st<<4) + lm;
      #pragma unroll
      for(int kb=0;kb<8;kb++){
        bf16x8 bfr = *(const bf16x8*)&Bt[(sg<<8) + (kb<<5) + lk];
        a = __builtin_amdgcn_mfma_f32_16x16x32_bf16(af[kb], bfr, a, 0,0,0);
      }
      #pragma unroll
      for(int r4=0;r4<4;r4++)
        ub[UIDX((wv<<4)+rr+r4, (st<<4)+lm)] = f2bf(a[r4]);
    }
    __syncthreads();
    // local scan (in-place uB -> h), zero rows past sequence end
    if(tid < 128){
      int s = (e8<<7) + tid;
      float Av = A[s];
      float h = bound[(((b<<5)+c)<<10) + s];
      #pragma unroll
      for(int t=0;t<64;t++){
        h = Av*h + bf2f(ub[UIDX(t, tid)]);
        ub[UIDX(t, tid)] = (t0 + 10 + t < SEQn) ? f2bf(h) : (unsigned short)0;
      }
    }
    __syncthreads();
    // C GEMM partial over this eighth's 128 s
    bf16x8 ah[4];
    #pragma unroll
    for(int kb=0;kb<4;kb++)
      ah[kb] = *(const bf16x8*)&ub[UIDX((wv<<4)+lm, (kb<<5)+lk)];
    #pragma unroll
    for(int nt=0;nt<16;nt++){
      int o = (nt<<4) + lm;
      #pragma unroll
      for(int kb=0;kb<4;kb++){
        bf16x8 bfr = *(const bf16x8*)&Ct[(o<<10) + (e8<<7) + (kb<<5) + lk];
        accC[nt] = __builtin_amdgcn_mfma_f32_16x16x32_bf16(ah[kb], bfr, accC[nt], 0,0,0);
      }
    }
  }
  #pragma unroll
  for(int nt=0;nt<16;nt++)
    #pragma unroll
    for(int r4=0;r4<4;r4++){
      int m = (wv<<4) + rr + r4;
      int o = (nt<<4) + lm;
      size_t idx = ((size_t)b*SEQn + t0 + m)*DOUTn + o;
      out[idx] += accC[nt][r4];
    }
}

extern "C" void kernel_launch(void* const* d_in, const int* in_sizes, int n_in,
                              void* d_out, int out_size, void* d_ws, size_t ws_size,
                              hipStream_t stream){
  const float* x  = (const float*)d_in[0];
  const float* h0 = (const float*)d_in[1];
  const float* A  = (const float*)d_in[2];
  const float* B  = (const float*)d_in[3];
  const float* C  = (const float*)d_in[4];
  const float* M  = (const float*)d_in[5];
  float* out = (float*)d_out;
  unsigned short* Bt = (unsigned short*)d_ws;            // 512 KB
  unsigned short* Ct = Bt + DIN*DST;                     // 512 KB
  unsigned short* Mt = Ct + DST*DOUTn;                   // 1.25 MB
  float* P     = (float*)((char*)d_ws + (4u<<20));       // 2 MB
  float* bound = (float*)((char*)d_ws + (6u<<20));       // 2 MB
  k_prep<<<512, 256, 0, stream>>>(B, C, M, Bt, Ct, Mt);
  k_ar<<<BSZn*NCH, 256, 0, stream>>>(x, Mt, out);
  k_part<<<BSZn*NCH, 256, 0, stream>>>(x, Bt, A, P);
  k_bound<<<(BSZn*DST)/256, 256, 0, stream>>>(A, h0, P, bound);
  k_scanc<<<BSZn*NCH, 256, 0, stream>>>(x, Bt, Ct, A, bound, out);
}

// Round 2
// 301.832 us; speedup vs baseline: 1.9233x; 1.9233x over previous
//
#include <hip/hip_runtime.h>

#define BSZn 16
#define SEQn 2048
#define DIN 256
#define DST 1024
#define DOUTn 256
#define KXn 10
#define TCH 64
#define NCH 32

typedef __attribute__((ext_vector_type(4))) float f32x4;
typedef __attribute__((ext_vector_type(8))) short bf16x8;

__device__ __forceinline__ unsigned short f2bf(float f){
  unsigned u = __float_as_uint(f);
  u += 0x7FFF + ((u>>16)&1);
  return (unsigned short)(u>>16);
}
__device__ __forceinline__ float bf2f(unsigned short s){
  return __uint_as_float(((unsigned)s)<<16);
}

// XOR-swizzled LDS element index for [*][256] bf16 tiles (row stride 512B)
#define XIDX(r,c) ((((r)<<8) + (c)) ^ (((r)&7)<<3))
// and [*][128] tiles (row stride 256B)
#define UIDX(r,c) ((((r)<<7) + (c)) ^ (((r)&7)<<3))

// ---------------- K0: weight prep (transpose + fp32->bf16) ----------------
__global__ void k_prep(const float* __restrict__ B, const float* __restrict__ C,
                       const float* __restrict__ M, unsigned short* __restrict__ Bt,
                       unsigned short* __restrict__ Ct, unsigned short* __restrict__ Mt){
  int stride = gridDim.x*blockDim.x;
  int i0 = blockIdx.x*blockDim.x + threadIdx.x;
  for(int idx=i0; idx<DIN*DST; idx+=stride){
    int s = idx >> 8, d = idx & 255;
    Bt[idx] = f2bf(B[d*DST + s]);          // Bt[s][d]
    int o = idx >> 10, ss = idx & 1023;
    Ct[idx] = f2bf(C[ss*DOUTn + o]);       // Ct[o][s]
  }
  for(int idx=i0; idx<DOUTn*DIN*KXn; idx+=stride){
    int o = idx/2560, k = idx%2560, ii = k>>8, j = k&255;
    Mt[idx] = f2bf(M[(o*DIN+j)*KXn + ii]); // Mt[o][i*256+j]
  }
}

// ---------------- K1: uB = x@B  (write bf16 [b][t][s]) + chunk partials P ----
__global__ __launch_bounds__(256) void k_ub(const float* __restrict__ x,
    const unsigned short* __restrict__ Bt, const float* __restrict__ A,
    unsigned short* __restrict__ uB, float* __restrict__ P){
  __shared__ __align__(16) unsigned short xt[64*256];   // x tile, then reused as uB tile
  int wg = blockIdx.x;
  int q = wg & 3, c = (wg>>2)&31, b = wg>>7;
  int t0 = c*TCH, s0 = q<<8;
  const float* xb = x + (size_t)b*SEQn*DIN;
  int tid = threadIdx.x;
  for(int e = tid; e < 64*64; e += 256){
    int r = e>>6, c4 = (e&63)<<2;
    float4 v = *(const float4*)(xb + (t0+r)*DIN + c4);
    ushort4 w; w.x=f2bf(v.x); w.y=f2bf(v.y); w.z=f2bf(v.z); w.w=f2bf(v.w);
    *(ushort4*)&xt[XIDX(r,c4)] = w;
  }
  __syncthreads();
  int wv = tid>>6, ln = tid&63, lm = ln&15, lk = (ln>>4)<<3, rr = (ln>>4)<<2;
  f32x4 zf = {0.f,0.f,0.f,0.f};
  f32x4 acc[4][4];
  #pragma unroll
  for(int tt=0;tt<4;tt++)
    #pragma unroll
    for(int nt=0;nt<4;nt++) acc[tt][nt] = zf;
  #pragma unroll
  for(int kb=0;kb<8;kb++){
    bf16x8 af[4];
    #pragma unroll
    for(int tt=0;tt<4;tt++)
      af[tt] = *(const bf16x8*)&xt[XIDX((tt<<4)+lm, (kb<<5)+lk)];
    #pragma unroll
    for(int nt=0;nt<4;nt++){
      int sg = s0 + (wv<<6) + (nt<<4) + lm;
      bf16x8 bfr = *(const bf16x8*)&Bt[(sg<<8) + (kb<<5) + lk];
      #pragma unroll
      for(int tt=0;tt<4;tt++)
        acc[tt][nt] = __builtin_amdgcn_mfma_f32_16x16x32_bf16(af[tt], bfr, acc[tt][nt], 0,0,0);
    }
  }
  __syncthreads();
  // acc -> LDS uB tile [64][256] (s-local), swizzled
  #pragma unroll
  for(int tt=0;tt<4;tt++)
    #pragma unroll
    for(int nt=0;nt<4;nt++)
      #pragma unroll
      for(int r4=0;r4<4;r4++)
        xt[XIDX((tt<<4)+rr+r4, (wv<<6)+(nt<<4)+lm)] = f2bf(acc[tt][nt][r4]);
  __syncthreads();
  // coalesced tile write to HBM
  unsigned short* uBp = uB + ((size_t)(b*SEQn + t0))*DST + s0;
  #pragma unroll
  for(int it=0; it<8; it++){
    int j = it*256 + tid;
    int r = j>>5, c0 = (j&31)<<3;
    bf16x8 v = *(const bf16x8*)&xt[XIDX(r,c0)];
    *(bf16x8*)&uBp[(size_t)r*DST + c0] = v;
  }
  // chunk partial: P[b][c][s] = sum_t A^(63-t) uB[t]
  {
    int s = s0 + tid;
    float Av = A[s];
    float p = 0.f;
    #pragma unroll
    for(int t=0;t<64;t++)
      p = fmaf(Av, p, bf2f(xt[XIDX(t, tid)]));
    P[(((b<<5)+c)<<10) + s] = p;
  }
}

// ---------------- K2: boundary states E[c] = state entering chunk c ---------
__global__ void k_bound(const float* __restrict__ A, const float* __restrict__ h0,
                        const float* __restrict__ P, float* __restrict__ bound){
  int i = blockIdx.x*blockDim.x + threadIdx.x;
  if(i >= BSZn*DST) return;
  int b = i >> 10, s = i & 1023;
  float Av = A[s];
  float a2=Av*Av, a4=a2*a2, a8=a4*a4, a16=a8*a8, a32=a16*a16, a64=a32*a32;
  const float* Pb = P + ((size_t)(b<<5)<<10);
  float* Bb = bound + ((size_t)(b<<5)<<10);
  float h = h0[s];
  Bb[s] = h;
  for(int c=1;c<NCH;c++){
    h = fmaf(a64, h, Pb[((c-1)<<10)+s]);
    Bb[(c<<10)+s] = h;
  }
}

// ---------------- K3: fully-parallel rescan, h overwrites uB in place -------
__global__ __launch_bounds__(256) void k_h(unsigned short* __restrict__ uB,
    const float* __restrict__ A, const float* __restrict__ bound){
  int wg = blockIdx.x;
  int q = wg & 1, c = (wg>>1)&31, b = wg>>6;
  int tid = threadIdx.x;
  int s = (q<<9) + (tid<<1);
  float Av0 = A[s], Av1 = A[s+1];
  const float* bp = bound + (((size_t)(b<<5)+c)<<10) + s;
  float hv0 = bp[0], hv1 = bp[1];
  unsigned* p = (unsigned*)(uB + ((size_t)(b*SEQn + c*TCH))*DST + s);
  #pragma unroll 8
  for(int t=0;t<64;t++){
    unsigned v = p[(size_t)t*512];
    hv0 = fmaf(Av0, hv0, bf2f((unsigned short)(v & 0xffff)));
    hv1 = fmaf(Av1, hv1, bf2f((unsigned short)(v >> 16)));
    unsigned o = (unsigned)f2bf(hv0) | (((unsigned)f2bf(hv1))<<16);
    p[(size_t)t*512] = o;
  }
}

// ---------------- K4: fused AR-GEMM + C-GEMM, single out write --------------
__global__ __launch_bounds__(256) void k_arc(const float* __restrict__ x,
    const unsigned short* __restrict__ Mt, const unsigned short* __restrict__ Ct,
    const unsigned short* __restrict__ hB, float* __restrict__ out){
  __shared__ __align__(16) unsigned short xt[73*256];
  __shared__ __align__(16) unsigned short ht[2][64*128];
  int wg = blockIdx.x;
  int b = wg>>5, c = wg&31;
  int t0 = c*TCH;
  const float* xb = x + (size_t)b*SEQn*DIN;
  int tid = threadIdx.x;
  // stage x rows t0-9 .. t0+63
  for(int e = tid; e < 73*64; e += 256){
    int r = e>>6, c4 = (e&63)<<2;
    int t = t0 - 9 + r;
    float4 v = {0.f,0.f,0.f,0.f};
    if(t >= 0) v = *(const float4*)(xb + t*DIN + c4);
    ushort4 w; w.x=f2bf(v.x); w.y=f2bf(v.y); w.z=f2bf(v.z); w.w=f2bf(v.w);
    *(ushort4*)&xt[XIDX(r, c4)] = w;
  }
  // stage h eighth 0 into buf 0 (h rows t0+10 .. t0+73, zero past end)
  const size_t hbase = (size_t)b*SEQn*DST;
  {
    #pragma unroll
    for(int it=0;it<4;it++){
      int j = it*256 + tid;
      int r = j>>4, c0 = (j&15)<<3;
      int t = t0 + 10 + r;
      bf16x8 v = {0,0,0,0,0,0,0,0};
      if(t < SEQn) v = *(const bf16x8*)&hB[hbase + (size_t)t*DST + c0];
      *(bf16x8*)&ht[0][UIDX(r,c0)] = v;
    }
  }
  __syncthreads();
  int wv = tid>>6, ln = tid&63, lm = ln&15, lk = (ln>>4)<<3, rr = (ln>>4)<<2;
  f32x4 zf = {0.f,0.f,0.f,0.f};
  f32x4 acc[4][4];
  #pragma unroll
  for(int tt=0;tt<4;tt++)
    #pragma unroll
    for(int nt=0;nt<4;nt++) acc[tt][nt] = zf;
  // ---- AR GEMM: K = 10*256 ----
  for(int i=0;i<KXn;i++){
    #pragma unroll
    for(int kb8=0;kb8<8;kb8++){
      int col = (kb8<<5) + lk;
      bf16x8 af[4];
      #pragma unroll
      for(int tt=0;tt<4;tt++)
        af[tt] = *(const bf16x8*)&xt[XIDX((tt<<4)+lm + 9 - i, col)];
      #pragma unroll
      for(int nt=0;nt<4;nt++){
        int o = (wv<<6) + (nt<<4) + lm;
        bf16x8 bfr = *(const bf16x8*)&Mt[o*2560 + (i<<8) + col];
        #pragma unroll
        for(int tt=0;tt<4;tt++)
          acc[tt][nt] = __builtin_amdgcn_mfma_f32_16x16x32_bf16(af[tt], bfr, acc[tt][nt], 0,0,0);
      }
    }
  }
  // ---- C GEMM: K = 1024 in 8 eighths, double-buffered h tiles ----
  for(int e8=0;e8<8;e8++){
    int buf = e8 & 1;
    if(e8 < 7){
      int nb = buf ^ 1;
      #pragma unroll
      for(int it=0;it<4;it++){
        int j = it*256 + tid;
        int r = j>>4, c0 = (j&15)<<3;
        int t = t0 + 10 + r;
        bf16x8 v = {0,0,0,0,0,0,0,0};
        if(t < SEQn) v = *(const bf16x8*)&hB[hbase + (size_t)t*DST + ((e8+1)<<7) + c0];
        *(bf16x8*)&ht[nb][UIDX(r,c0)] = v;
      }
    }
    bf16x8 ah[4][4];
    #pragma unroll
    for(int tt=0;tt<4;tt++)
      #pragma unroll
      for(int kb=0;kb<4;kb++)
        ah[tt][kb] = *(const bf16x8*)&ht[buf][UIDX((tt<<4)+lm, (kb<<5)+lk)];
    #pragma unroll
    for(int nt=0;nt<4;nt++){
      int o = (wv<<6) + (nt<<4) + lm;
      #pragma unroll
      for(int kb=0;kb<4;kb++){
        bf16x8 bfr = *(const bf16x8*)&Ct[(o<<10) + (e8<<7) + (kb<<5) + lk];
        #pragma unroll
        for(int tt=0;tt<4;tt++)
          acc[tt][nt] = __builtin_amdgcn_mfma_f32_16x16x32_bf16(ah[tt][kb], bfr, acc[tt][nt], 0,0,0);
      }
    }
    __syncthreads();
  }
  // ---- single write ----
  #pragma unroll
  for(int tt=0;tt<4;tt++)
    #pragma unroll
    for(int nt=0;nt<4;nt++)
      #pragma unroll
      for(int r4=0;r4<4;r4++){
        int m = (tt<<4) + rr + r4;
        int o = (wv<<6) + (nt<<4) + lm;
        out[((size_t)b*SEQn + t0 + m)*DOUTn + o] = acc[tt][nt][r4];
      }
}

extern "C" void kernel_launch(void* const* d_in, const int* in_sizes, int n_in,
                              void* d_out, int out_size, void* d_ws, size_t ws_size,
                              hipStream_t stream){
  const float* x  = (const float*)d_in[0];
  const float* h0 = (const float*)d_in[1];
  const float* A  = (const float*)d_in[2];
  const float* B  = (const float*)d_in[3];
  const float* C  = (const float*)d_in[4];
  const float* M  = (const float*)d_in[5];
  float* out = (float*)d_out;
  unsigned short* Bt = (unsigned short*)d_ws;                  // 512 KB
  unsigned short* Ct = Bt + DIN*DST;                           // 512 KB
  unsigned short* Mt = Ct + DST*DOUTn;                         // 1.31 MB
  float* P     = (float*)((char*)d_ws + ( 4u<<20));            // 2 MB
  float* bound = (float*)((char*)d_ws + ( 6u<<20));            // 2 MB
  unsigned short* uB = (unsigned short*)((char*)d_ws + (8u<<20)); // 67.1 MB (uB, then h in place)
  k_prep <<<512, 256, 0, stream>>>(B, C, M, Bt, Ct, Mt);
  k_ub   <<<BSZn*NCH*4, 256, 0, stream>>>(x, Bt, A, uB, P);
  k_bound<<<(BSZn*DST)/256, 256, 0, stream>>>(A, h0, P, bound);
  k_h    <<<BSZn*NCH*2, 256, 0, stream>>>(uB, A, bound);
  k_arc  <<<BSZn*NCH, 256, 0, stream>>>(x, Mt, Ct, uB, out);
}

// Round 3
// 238.433 us; speedup vs baseline: 2.4347x; 1.2659x over previous
//
#include <hip/hip_runtime.h>

#define BSZn 16
#define SEQn 2048
#define DIN 256
#define DST 1024
#define DOUTn 256
#define KXn 10
#define TCH 64
#define NCH 32
#define ROWSB 2064   // rows per batch in uB/h2 buffer (2048 + 16 zero tail)

typedef __attribute__((ext_vector_type(4))) float f32x4;
typedef __attribute__((ext_vector_type(8))) short bf16x8;

__device__ __forceinline__ unsigned short f2bf(float f){
  unsigned u = __float_as_uint(f);
  u += 0x7FFF + ((u>>16)&1);
  return (unsigned short)(u>>16);
}
__device__ __forceinline__ float bf2f(unsigned short s){
  return __uint_as_float(((unsigned)s)<<16);
}

// XOR-swizzled LDS element index for [*][256] bf16 tiles (row stride 512B)
#define XIDX(r,c) ((((r)<<8) + (c)) ^ (((r)&7)<<3))

// ---------------- K0: weight prep -> fragment-major bf16 ----------------
// Bt2[(d>>5)][s][d&31], Ct2[(s>>5)][o][s&31], Mt2[(k>>5)][o][k&31], k=i*256+j
__global__ void k_prep(const float* __restrict__ B, const float* __restrict__ C,
                       const float* __restrict__ M, unsigned short* __restrict__ Bt2,
                       unsigned short* __restrict__ Ct2, unsigned short* __restrict__ Mt2){
  int stride = gridDim.x*blockDim.x;
  int i0 = blockIdx.x*blockDim.x + threadIdx.x;
  for(int idx=i0; idx<DIN*DST; idx+=stride){
    int kb = idx>>15, s = (idx>>5)&1023, dl = idx&31;
    int d = (kb<<5)+dl;
    Bt2[idx] = f2bf(B[d*DST + s]);
  }
  for(int idx=i0; idx<DST*DOUTn; idx+=stride){
    int kb = idx>>13, o = (idx>>5)&255, sl = idx&31;
    int s = (kb<<5)+sl;
    Ct2[idx] = f2bf(C[s*DOUTn + o]);
  }
  for(int idx=i0; idx<DOUTn*DIN*KXn; idx+=stride){
    int kq = idx>>13, o = (idx>>5)&255, kl = idx&31;
    int k = (kq<<5)+kl, ii = k>>8, j = k&255;
    Mt2[idx] = f2bf(M[(o*DIN+j)*KXn + ii]);
  }
}

// ---------------- K1: uB = x@B (bf16, row-major, stride ROWSB) + partials P ----
__global__ __launch_bounds__(256) void k_ub(const float* __restrict__ x,
    const unsigned short* __restrict__ Bt2, const float* __restrict__ A,
    unsigned short* __restrict__ uB, float* __restrict__ P){
  __shared__ __align__(16) unsigned short xt[64*256];
  int wg = blockIdx.x;
  int q = wg & 3, c = (wg>>2)&31, b = wg>>7;
  int t0 = c*TCH, s0 = q<<8;
  const float* xb = x + (size_t)b*SEQn*DIN;
  int tid = threadIdx.x;
  for(int e = tid; e < 64*64; e += 256){
    int r = e>>6, c4 = (e&63)<<2;
    float4 v = *(const float4*)(xb + (t0+r)*DIN + c4);
    ushort4 w; w.x=f2bf(v.x); w.y=f2bf(v.y); w.z=f2bf(v.z); w.w=f2bf(v.w);
    *(ushort4*)&xt[XIDX(r,c4)] = w;
  }
  __syncthreads();
  int wv = tid>>6, ln = tid&63, lm = ln&15, lk = (ln>>4)<<3, rr = (ln>>4)<<2;
  f32x4 zf = {0.f,0.f,0.f,0.f};
  f32x4 acc[4][4];
  #pragma unroll
  for(int tt=0;tt<4;tt++)
    #pragma unroll
    for(int nt=0;nt<4;nt++) acc[tt][nt] = zf;
  #pragma unroll
  for(int kb=0;kb<8;kb++){
    bf16x8 af[4];
    #pragma unroll
    for(int tt=0;tt<4;tt++)
      af[tt] = *(const bf16x8*)&xt[XIDX((tt<<4)+lm, (kb<<5)+lk)];
    #pragma unroll
    for(int nt=0;nt<4;nt++){
      int sg = s0 + (wv<<6) + (nt<<4) + lm;
      bf16x8 bfr = *(const bf16x8*)&Bt2[(kb<<15) + (sg<<5) + lk];
      #pragma unroll
      for(int tt=0;tt<4;tt++)
        acc[tt][nt] = __builtin_amdgcn_mfma_f32_16x16x32_bf16(af[tt], bfr, acc[tt][nt], 0,0,0);
    }
  }
  __syncthreads();
  #pragma unroll
  for(int tt=0;tt<4;tt++)
    #pragma unroll
    for(int nt=0;nt<4;nt++)
      #pragma unroll
      for(int r4=0;r4<4;r4++)
        xt[XIDX((tt<<4)+rr+r4, (wv<<6)+(nt<<4)+lm)] = f2bf(acc[tt][nt][r4]);
  __syncthreads();
  unsigned short* uBp = uB + ((size_t)b*ROWSB + t0)*DST + s0;
  #pragma unroll
  for(int it=0; it<8; it++){
    int j = it*256 + tid;
    int r = j>>5, c0 = (j&31)<<3;
    bf16x8 v = *(const bf16x8*)&xt[XIDX(r,c0)];
    *(bf16x8*)&uBp[(size_t)r*DST + c0] = v;
  }
  {
    int s = s0 + tid;
    float Av = A[s];
    float p = 0.f;
    #pragma unroll
    for(int t=0;t<64;t++)
      p = fmaf(Av, p, bf2f(xt[XIDX(t, tid)]));
    P[(((b<<5)+c)<<10) + s] = p;
  }
}

// ---------------- K2: boundary states entering each chunk ----------------
__global__ void k_bound(const float* __restrict__ A, const float* __restrict__ h0,
                        const float* __restrict__ P, float* __restrict__ bound){
  int i = blockIdx.x*blockDim.x + threadIdx.x;
  if(i >= BSZn*DST) return;
  int b = i >> 10, s = i & 1023;
  float Av = A[s];
  float a2=Av*Av, a4=a2*a2, a8=a4*a4, a16=a8*a8, a32=a16*a16, a64=a32*a32;
  const float* Pb = P + ((size_t)(b<<5)<<10);
  float* Bb = bound + ((size_t)(b<<5)<<10);
  float h = h0[s];
  Bb[s] = h;
  for(int c=1;c<NCH;c++){
    h = fmaf(a64, h, Pb[((c-1)<<10)+s]);
    Bb[(c<<10)+s] = h;
  }
}

// ---------------- K3: scan + in-place re-layout uB -> h2 (fragment-major) ----
// h2 element (t,s) at ((b*129 + (t>>4))*32 + (s>>5))*512 + (t&15)*32 + (s&31)
__global__ __launch_bounds__(256) void k_h(unsigned short* __restrict__ uB,
    const float* __restrict__ A, const float* __restrict__ bound){
  int wg = blockIdx.x;
  int c = wg & 31, b = wg >> 5;
  int tid = threadIdx.x;
  int s = tid << 2;
  float Av[4], h[4];
  const float* bp = bound + (((size_t)(b<<5)+c)<<10) + s;
  #pragma unroll
  for(int j=0;j<4;j++){ Av[j] = A[s+j]; h[j] = bp[j]; }
  unsigned short* base = uB + ((size_t)b*ROWSB + c*TCH)*DST;
  int kb = s>>5, sl = s&31;
  for(int T=0; T<4; T++){
    unsigned v[16][2];
    #pragma unroll
    for(int r=0;r<16;r++){
      const unsigned* p = (const unsigned*)(base + (size_t)(T*16+r)*DST + s);
      v[r][0] = p[0]; v[r][1] = p[1];
    }
    __syncthreads();   // all reads of this 16-row block done before any rewrite
    #pragma unroll
    for(int r=0;r<16;r++){
      float u0 = bf2f((unsigned short)(v[r][0]&0xffff)), u1 = bf2f((unsigned short)(v[r][0]>>16));
      float u2 = bf2f((unsigned short)(v[r][1]&0xffff)), u3 = bf2f((unsigned short)(v[r][1]>>16));
      h[0] = fmaf(Av[0],h[0],u0); h[1] = fmaf(Av[1],h[1],u1);
      h[2] = fmaf(Av[2],h[2],u2); h[3] = fmaf(Av[3],h[3],u3);
      v[r][0] = (unsigned)f2bf(h[0]) | (((unsigned)f2bf(h[1]))<<16);
      v[r][1] = (unsigned)f2bf(h[2]) | (((unsigned)f2bf(h[3]))<<16);
    }
    unsigned* wp = (unsigned*)(uB + (((size_t)b*129 + c*4 + T)*32 + kb)*512 + sl);
    #pragma unroll
    for(int r=0;r<16;r++){
      wp[r*16]   = v[r][0];
      wp[r*16+1] = v[r][1];
    }
    __syncthreads();
  }
  if(c == 31){
    unsigned* zp = (unsigned*)(uB + (((size_t)b*129 + 128)*32)*512);
    for(int e = tid; e < 8192; e += 256) zp[e] = 0u;
  }
}

// ---------------- K4: AR-GEMM + C-GEMM, h fragments direct from global -------
__global__ __launch_bounds__(256) void k_arc(const float* __restrict__ x,
    const unsigned short* __restrict__ Mt2, const unsigned short* __restrict__ Ct2,
    const unsigned short* __restrict__ h2, float* __restrict__ out){
  __shared__ __align__(16) unsigned short xt[73*256];
  int wg = blockIdx.x;
  int b = wg>>5, c = wg&31;
  int t0 = c*TCH;
  const float* xb = x + (size_t)b*SEQn*DIN;
  int tid = threadIdx.x;
  for(int e = tid; e < 73*64; e += 256){
    int r = e>>6, c4 = (e&63)<<2;
    int t = t0 - 9 + r;
    float4 v = {0.f,0.f,0.f,0.f};
    if(t >= 0) v = *(const float4*)(xb + t*DIN + c4);
    ushort4 w; w.x=f2bf(v.x); w.y=f2bf(v.y); w.z=f2bf(v.z); w.w=f2bf(v.w);
    *(ushort4*)&xt[XIDX(r, c4)] = w;
  }
  __syncthreads();
  int wv = tid>>6, ln = tid&63, lm = ln&15, lk = (ln>>4)<<3, rr = (ln>>4)<<2;
  f32x4 zf = {0.f,0.f,0.f,0.f};
  f32x4 acc[4][4];
  #pragma unroll
  for(int tt=0;tt<4;tt++)
    #pragma unroll
    for(int nt=0;nt<4;nt++) acc[tt][nt] = zf;
  // ---- AR GEMM: K = 10*256, coalesced Mt2 fragments ----
  for(int i=0;i<KXn;i++){
    #pragma unroll
    for(int kb8=0;kb8<8;kb8++){
      int col = (kb8<<5) + lk;
      int kq = i*8 + kb8;
      bf16x8 af[4];
      #pragma unroll
      for(int tt=0;tt<4;tt++)
        af[tt] = *(const bf16x8*)&xt[XIDX((tt<<4)+lm + 9 - i, col)];
      #pragma unroll
      for(int nt=0;nt<4;nt++){
        int o = (wv<<6) + (nt<<4) + lm;
        bf16x8 bfr = *(const bf16x8*)&Mt2[(kq<<13) + (o<<5) + lk];
        #pragma unroll
        for(int tt=0;tt<4;tt++)
          acc[tt][nt] = __builtin_amdgcn_mfma_f32_16x16x32_bf16(af[tt], bfr, acc[tt][nt], 0,0,0);
      }
    }
  }
  // ---- C GEMM: K = 1024, h rows t0+10..t0+73 direct from h2 (split base) ----
  const unsigned short* hb = h2 + (size_t)b*129*32*512;
  int Tg0 = c*4 + (lm>=6 ? 1 : 0);
  int rowin = (lm<6) ? (10+lm) : (lm-6);
  for(int kb=0;kb<32;kb++){
    bf16x8 af[4];
    #pragma unroll
    for(int tt=0;tt<4;tt++)
      af[tt] = *(const bf16x8*)&hb[(((size_t)(Tg0+tt))*32 + kb)*512 + rowin*32 + lk];
    #pragma unroll
    for(int nt=0;nt<4;nt++){
      int o = (wv<<6) + (nt<<4) + lm;
      bf16x8 bfr = *(const bf16x8*)&Ct2[(kb<<13) + (o<<5) + lk];
      #pragma unroll
      for(int tt=0;tt<4;tt++)
        acc[tt][nt] = __builtin_amdgcn_mfma_f32_16x16x32_bf16(af[tt], bfr, acc[tt][nt], 0,0,0);
    }
  }
  #pragma unroll
  for(int tt=0;tt<4;tt++)
    #pragma unroll
    for(int nt=0;nt<4;nt++)
      #pragma unroll
      for(int r4=0;r4<4;r4++){
        int m = (tt<<4) + rr + r4;
        int o = (wv<<6) + (nt<<4) + lm;
        out[((size_t)b*SEQn + t0 + m)*DOUTn + o] = acc[tt][nt][r4];
      }
}

extern "C" void kernel_launch(void* const* d_in, const int* in_sizes, int n_in,
                              void* d_out, int out_size, void* d_ws, size_t ws_size,
                              hipStream_t stream){
  const float* x  = (const float*)d_in[0];
  const float* h0 = (const float*)d_in[1];
  const float* A  = (const float*)d_in[2];
  const float* B  = (const float*)d_in[3];
  const float* C  = (const float*)d_in[4];
  const float* M  = (const float*)d_in[5];
  float* out = (float*)d_out;
  unsigned short* Bt2 = (unsigned short*)d_ws;                   // 512 KB
  unsigned short* Ct2 = Bt2 + DIN*DST;                           // 512 KB
  unsigned short* Mt2 = Ct2 + DST*DOUTn;                         // 1.31 MB
  float* P     = (float*)((char*)d_ws + ( 4u<<20));              // 2 MB
  float* bound = (float*)((char*)d_ws + ( 6u<<20));              // 2 MB
  unsigned short* uB = (unsigned short*)((char*)d_ws + (8u<<20)); // 64.5 MB (uB -> h2 in place)
  k_prep <<<512, 256, 0, stream>>>(B, C, M, Bt2, Ct2, Mt2);
  k_ub   <<<BSZn*NCH*4, 256, 0, stream>>>(x, Bt2, A, uB, P);
  k_bound<<<(BSZn*DST)/256, 256, 0, stream>>>(A, h0, P, bound);
  k_h    <<<BSZn*NCH, 256, 0, stream>>>(uB, A, bound);
  k_arc  <<<BSZn*NCH, 256, 0, stream>>>(x, Mt2, Ct2, uB, out);
}